// Round 1
// baseline (143.036 us; speedup 1.0000x reference)
//
#include <hip/hip_runtime.h>
#include <math.h>

// Problem constants (fixed by reference): B=32, T=2048, D=128
constexpr int B  = 32;
constexpr int T  = 2048;
constexpr int D  = 128;
constexpr int C  = 16;          // timesteps per thread (chunk)
constexpr int NC = T / C;       // 128 chunks per sequence

// One thread owns timesteps [chunk*C, chunk*C+C) of sequence (b,d).
// Thread order: d fastest -> consecutive lanes read consecutive d -> coalesced.
__global__ __launch_bounds__(256)
void linterp_kernel(const float* __restrict__ values,
                    const float* __restrict__ times,
                    const int*   __restrict__ mask,
                    float*       __restrict__ out)
{
    const int gid   = blockIdx.x * 256 + threadIdx.x;
    const int d     = gid & (D - 1);
    const int chunk = (gid >> 7) & (NC - 1);   // D = 2^7
    const int b     = gid >> 14;               // D*NC = 2^14

    const int seq_base = b * T * D + d;        // element offset of (b, t=0, d)
    const int t0i      = chunk * C;

    // ---- load chunk into registers ----
    float v[C], tm[C];
    unsigned int mbits = 0;
#pragma unroll
    for (int i = 0; i < C; ++i) {
        const int off = seq_base + (t0i + i) * D;
        v[i]  = values[off];
        tm[i] = times[off];
        mbits |= (mask[off] != 0 ? 1u : 0u) << i;
    }

    // defaults for "no observation" match reference init values exactly:
    //   forward : x=0, t=times[b,0,d]      backward: x=0, t=times[b,T-1,d]
    // (times is a cumsum of non-negative uniforms -> max over t == last element)
    const float t_first = times[seq_base];
    const float t_lastT = times[seq_base + (T - 1) * D];

    // ---- forward carry: last observed element strictly before this chunk ----
    // Expected ~1 iteration at 50% mask density.
    float fx = 0.f, ft = t_first;
    for (int j = t0i - 1; j >= 0; --j) {
        const int off = seq_base + j * D;
        if (mask[off] != 0) { fx = values[off]; ft = times[off]; break; }
    }

    // ---- backward carry: first observed element strictly after this chunk ----
    float bx = 0.f, bt = t_lastT;
    for (int j = t0i + C; j < T; ++j) {
        const int off = seq_base + j * D;
        if (mask[off] != 0) { bx = values[off]; bt = times[off]; break; }
    }

    // ---- forward pass: x_last / t_last per element (cummax incl. current) ----
    float xl[C], tl[C];
#pragma unroll
    for (int i = 0; i < C; ++i) {
        if ((mbits >> i) & 1u) { fx = v[i]; ft = tm[i]; }
        xl[i] = fx;
        tl[i] = ft;
    }

    // ---- reverse pass: x_next / t_next on the fly, combine, store ----
#pragma unroll
    for (int i = C - 1; i >= 0; --i) {
        const bool obs = (mbits >> i) & 1u;
        if (obs) { bx = v[i]; bt = tm[i]; }
        const float denom = bt - tl[i];
        const float num   = xl[i] * (bt - tm[i]) + bx * (tm[i] - tl[i]);
        const bool  safe  = (denom != 0.f);
        float xi = num / (safe ? denom : 1.f);
        xi = (safe && isfinite(xi)) ? xi : 0.f;
        out[seq_base + (t0i + i) * D] = obs ? v[i] : xi;
    }
}

extern "C" void kernel_launch(void* const* d_in, const int* in_sizes, int n_in,
                              void* d_out, int out_size, void* d_ws, size_t ws_size,
                              hipStream_t stream)
{
    const float* values = (const float*)d_in[0];
    const float* times  = (const float*)d_in[1];
    const int*   mask   = (const int*)d_in[2];
    float*       out    = (float*)d_out;

    const int total_threads = B * NC * D;   // 524288
    linterp_kernel<<<total_threads / 256, 256, 0, stream>>>(values, times, mask, out);
}

// Round 2
// 134.222 us; speedup vs baseline: 1.0657x; 1.0657x over previous
//
#include <hip/hip_runtime.h>
#include <math.h>

// Problem constants (fixed by reference): B=32, T=2048, D=128
constexpr int B  = 32;
constexpr int T  = 2048;
constexpr int D  = 128;
constexpr int C  = 16;          // timesteps per thread (chunk)
constexpr int NC = T / C;       // 128 chunks per sequence

// One thread owns timesteps [chunk*C, chunk*C+C) of sequence (b,d).
// Thread order: d fastest -> consecutive lanes read consecutive d -> coalesced.
//
// Carry lookup strategy (R1): instead of a serial divergent probe loop
// (dependent load->branch per element, ~8 rounds of memory latency), load the
// adjacent chunk's 16 mask words unconditionally (independent -> 1 latency
// round), reduce to a bitmask, clz/ctz to the nearest observed index, then one
// dependent round to fetch its (value,time). Fallback serial loop only if the
// whole adjacent chunk is unobserved (P = 2^-16).
__global__ __launch_bounds__(256)
void linterp_kernel(const float* __restrict__ values,
                    const float* __restrict__ times,
                    const int*   __restrict__ mask,
                    float*       __restrict__ out)
{
    const int gid   = blockIdx.x * 256 + threadIdx.x;
    const int d     = gid & (D - 1);
    const int chunk = (gid >> 7) & (NC - 1);   // D = 2^7
    const int b     = gid >> 14;               // D*NC = 2^14

    const int seq_base = b * T * D + d;        // element offset of (b, t=0, d)
    const int t0i      = chunk * C;

    // ---- load chunk into registers (48 independent coalesced loads) ----
    float v[C], tm[C];
    unsigned int mbits = 0;
#pragma unroll
    for (int i = 0; i < C; ++i) {
        const int off = seq_base + (t0i + i) * D;
        v[i]  = values[off];
        tm[i] = times[off];
        mbits |= (mask[off] != 0 ? 1u : 0u) << i;
    }

    // defaults for "no observation" match reference init values exactly:
    //   forward : x=0, t=times[b,0,d]      backward: x=0, t=times[b,T-1,d]
    const float t_first = times[seq_base];
    const float t_lastT = times[seq_base + (T - 1) * D];

    // ---- forward carry: last observed element strictly before this chunk ----
    float fx = 0.f, ft = t_first;
    if (chunk > 0) {
        unsigned int pb = 0;
#pragma unroll
        for (int i = 0; i < C; ++i) {          // prev chunk's masks: independent
            const int off = seq_base + (t0i - C + i) * D;
            pb |= (mask[off] != 0 ? 1u : 0u) << i;
        }
        if (pb != 0u) {
            const int idx = 31 - __builtin_clz(pb);          // latest observed
            const int off = seq_base + (t0i - C + idx) * D;
            fx = values[off]; ft = times[off];
        } else {
            // rare fallback: scan further back
            for (int j = t0i - C - 1; j >= 0; --j) {
                const int off = seq_base + j * D;
                if (mask[off] != 0) { fx = values[off]; ft = times[off]; break; }
            }
        }
    }

    // ---- backward carry: first observed element strictly after this chunk ----
    float bx = 0.f, bt = t_lastT;
    if (chunk < NC - 1) {
        unsigned int nb = 0;
#pragma unroll
        for (int i = 0; i < C; ++i) {          // next chunk's masks: independent
            const int off = seq_base + (t0i + C + i) * D;
            nb |= (mask[off] != 0 ? 1u : 0u) << i;
        }
        if (nb != 0u) {
            const int idx = __builtin_ctz(nb);               // earliest observed
            const int off = seq_base + (t0i + C + idx) * D;
            bx = values[off]; bt = times[off];
        } else {
            // rare fallback: scan further forward
            for (int j = t0i + 2 * C; j < T; ++j) {
                const int off = seq_base + j * D;
                if (mask[off] != 0) { bx = values[off]; bt = times[off]; break; }
            }
        }
    }

    // ---- forward pass: x_last / t_last per element (cummax incl. current) ----
    float xl[C], tl[C];
#pragma unroll
    for (int i = 0; i < C; ++i) {
        if ((mbits >> i) & 1u) { fx = v[i]; ft = tm[i]; }
        xl[i] = fx;
        tl[i] = ft;
    }

    // ---- reverse pass: x_next / t_next on the fly, combine, store ----
#pragma unroll
    for (int i = C - 1; i >= 0; --i) {
        const bool obs = (mbits >> i) & 1u;
        if (obs) { bx = v[i]; bt = tm[i]; }
        const float denom = bt - tl[i];
        const float num   = xl[i] * (bt - tm[i]) + bx * (tm[i] - tl[i]);
        const bool  safe  = (denom != 0.f);
        float xi = num / (safe ? denom : 1.f);
        xi = (safe && isfinite(xi)) ? xi : 0.f;
        out[seq_base + (t0i + i) * D] = obs ? v[i] : xi;
    }
}

extern "C" void kernel_launch(void* const* d_in, const int* in_sizes, int n_in,
                              void* d_out, int out_size, void* d_ws, size_t ws_size,
                              hipStream_t stream)
{
    const float* values = (const float*)d_in[0];
    const float* times  = (const float*)d_in[1];
    const int*   mask   = (const int*)d_in[2];
    float*       out    = (float*)d_out;

    const int total_threads = B * NC * D;   // 524288
    linterp_kernel<<<total_threads / 256, 256, 0, stream>>>(values, times, mask, out);
}